// Round 3
// baseline (5629.763 us; speedup 1.0000x reference)
//
#include <hip/hip_runtime.h>
#include <math.h>

// Problem constants (fixed by the reference)
constexpr int N_ = 101, H_ = 128, NH_ = 8, HD_ = 16;
constexpr int SK = 129;              // padded LDS stride for Kh (bank-conflict-free)
constexpr float EPS_ = 1e-5f;

// LDS layout (float words) — total 15,199 words = 60,796 B (< 64 KiB)
constexpr int OFF_KH  = 0;                    // 101*129 = 13029
constexpr int OFF_BUF = OFF_KH + N_ * SK;     // 808: logits/attn, comp
constexpr int OFF_RED = OFF_BUF + NH_ * N_;   // 512: matvec reduce scratch
constexpr int OFF_MB  = OFF_RED + 512;        // 101 mask-this-step
constexpr int OFF_M1  = OFF_MB + N_;          // 101 visited mask
constexpr int OFF_DV  = OFF_M1 + N_;          // 128
constexpr int OFF_QV  = OFF_DV + H_;          // 128
constexpr int OFF_XV  = OFF_QV + H_;          // 128
constexpr int OFF_PP  = OFF_XV + H_;          // 128 pool_proc
constexpr int OFF_IV  = OFF_PP + H_;          // 128 current input row
constexpr int OFF_SC  = OFF_IV + H_;          // scalars: [0]=idx(int) [1]=cap [2]=lpsum [3]=vis(int)
constexpr int LDS_WORDS = OFF_SC + 8;

__global__ __launch_bounds__(512, 2) void gat_decoder(
    const float* __restrict__ enc, const float* __restrict__ pool,
    const float* __restrict__ capac, const float* __restrict__ dem,
    const float* __restrict__ fcw, const float* __restrict__ fc1w,
    const float* __restrict__ lng, const float* __restrict__ lnb,
    const float* __restrict__ wq, const float* __restrict__ wk,
    const float* __restrict__ wv, const float* __restrict__ wo,
    const float* __restrict__ kpw, const float* __restrict__ plg,
    const float* __restrict__ plb, const int* __restrict__ tp,
    float* __restrict__ out, int Bv, int ns)
{
  __shared__ float sm[LDS_WORDS];
  const int tid  = threadIdx.x;
  const int b    = blockIdx.x;
  const int lane = tid & 63;
  const int j    = tid & 127;   // output column
  const int s    = tid >> 7;    // k-slice 0..3
  const int w1   = (tid >> 6) & 1;  // which j-half this wave covers

  const float NEG_INF = -__builtin_inff();

  int ti = tp[0];
  float Tf = (ti > 1000000 || ti < -1000000) ? __int_as_float((int)ti) : (float)ti;

  const float inv_sqrt_hd = 0.25f;                 // 1/sqrt(16)
  const float inv_sqrt_h  = 1.0f / sqrtf(128.0f);

  const float* encb = enc + (size_t)b * (N_ * H_);

  float* KH = sm + OFF_KH;
  float* BUF = sm + OFF_BUF; float* RED = sm + OFF_RED;
  float* MB = sm + OFF_MB; float* M1 = sm + OFF_M1;
  float* DV = sm + OFF_DV; float* QV = sm + OFF_QV; float* XV = sm + OFF_XV;
  float* PP = sm + OFF_PP; float* IV = sm + OFF_IV;
  int*   SCI = ((int*)sm) + OFF_SC;
  float* SCF = sm + OFF_SC;

  const int g  = __builtin_amdgcn_readfirstlane(tid >> 7);  // wave-uniform row group
  const int r0 = g * 26;
  const int nr = (g == 3) ? 23 : 26;

  // ---------- precompute Kh into LDS ----------
  {
    float acc[26];
    #pragma unroll
    for (int t = 0; t < 26; ++t) acc[t] = 0.f;
    for (int k0 = 0; k0 < H_; k0 += 8) {
      float w8[8];
      #pragma unroll
      for (int kk = 0; kk < 8; ++kk) w8[kk] = wk[(k0 + kk) * H_ + j];
      #pragma unroll
      for (int t = 0; t < 26; ++t) {
        if (t < nr) {
          const float* ep = encb + (r0 + t) * H_ + k0;   // wave-uniform address
          #pragma unroll
          for (int kk = 0; kk < 8; ++kk) acc[t] = fmaf(ep[kk], w8[kk], acc[t]);
        }
      }
    }
    #pragma unroll
    for (int t = 0; t < 26; ++t)
      if (t < nr) KH[(r0 + t) * SK + j] = acc[t];
  }

  // ---------- Kp, Vh kept in REGISTERS: column slice [row r0+t][j] ----------
  float kp_r[26], vh_r[26];
  {
    #pragma unroll
    for (int t = 0; t < 26; ++t) { kp_r[t] = 0.f; vh_r[t] = 0.f; }
    for (int k0 = 0; k0 < H_; k0 += 8) {
      float wp8[8], wv8[8];
      #pragma unroll
      for (int kk = 0; kk < 8; ++kk) {
        wp8[kk] = kpw[(k0 + kk) * H_ + j];
        wv8[kk] = wv[(k0 + kk) * H_ + j];
      }
      #pragma unroll
      for (int t = 0; t < 26; ++t) {
        if (t < nr) {
          const float* ep = encb + (r0 + t) * H_ + k0;
          #pragma unroll
          for (int kk = 0; kk < 8; ++kk) {
            kp_r[t] = fmaf(ep[kk], wp8[kk], kp_r[t]);
            vh_r[t] = fmaf(ep[kk], wv8[kk], vh_r[t]);
          }
        }
      }
    }
  }

  // pool_proc partials
  {
    const float* pb = pool + (size_t)b * H_;
    float p = 0.f;
    #pragma unroll
    for (int r = 0; r < 32; ++r) p = fmaf(pb[s * 32 + r], fc1w[(s * 32 + r) * H_ + j], p);
    RED[s * H_ + j] = p;
  }
  for (int n = tid; n < N_; n += 512) M1[n] = 0.f;
  if (tid == 0) {
    SCI[0] = 0;              // current idx
    SCF[1] = capac[b];       // cap
    SCF[2] = 0.f;            // lp sum
    SCI[3] = 0;              // visited count
  }
  __syncthreads();
  if (tid < 128) PP[j] = RED[j] + RED[128 + j] + RED[256 + j] + RED[384 + j];
  __syncthreads();

  // ---------- weights into registers ----------
  float wq_r[32], wo_r[32], fc_r[32];
  #pragma unroll
  for (int r = 0; r < 32; ++r) {
    wq_r[r] = wq[(s * 32 + r) * H_ + j];
    wo_r[r] = wo[(s * 32 + r) * H_ + j];
    fc_r[r] = fcw[(s * 32 + r) * H_ + j];
  }
  const float fcap = fcw[128 * H_ + j];

  // ---------- decode loop ----------
  for (int i = 0; i < ns; ++i) {
    const int pidx = SCI[0];

    // Phase A: masks (wave 0) + input-row copy (waves 2,3)
    if (tid < 64) {
      const float cap = SCF[1];
      const bool newly = (i > 0) && (pidx != 0);
      const int n1 = lane, n2 = lane + 64;
      bool vis1 = (M1[n1] > 0.f) || (newly && n1 == pidx);
      bool inf1 = (n1 >= 1) && (vis1 || dem[(size_t)b * N_ + n1] > cap);
      bool feas1 = (n1 >= 1) && !inf1;
      bool inf2 = true, feas2 = false;
      if (n2 < N_) {
        bool vis2 = (M1[n2] > 0.f) || (newly && n2 == pidx);
        inf2 = vis2 || (dem[(size_t)b * N_ + n2] > cap);
        feas2 = !inf2;
      }
      const bool anyf = __any(feas1 || feas2);
      const bool allc = !anyf;
      const bool depot_m = allc ? false : ((i == 0) ? true : ((pidx == 0) && anyf));
      MB[n1] = (n1 == 0) ? (depot_m ? 1.f : 0.f) : (inf1 ? 1.f : 0.f);
      if (n2 < N_) MB[n2] = inf2 ? 1.f : 0.f;
      if (newly && (n1 == pidx || n2 == pidx)) {     // exactly one lane
        if (M1[pidx] == 0.f) { M1[pidx] = 1.f; SCI[3] = SCI[3] + 1; }
      }
    } else if (tid >= 128 && tid < 256) {
      IV[tid - 128] = encb[(size_t)pidx * H_ + (tid - 128)];
    }
    __syncthreads();

    // Phase B: d = [inp,cap]@fc_w + pool_proc ; LN
    {
      float part = 0.f;
      #pragma unroll
      for (int r = 0; r < 32; ++r) part = fmaf(fc_r[r], IV[s * 32 + r], part);
      RED[s * H_ + j] = part;
    }
    __syncthreads();
    if (tid < 128) {
      float dsum = RED[j] + RED[128 + j] + RED[256 + j] + RED[384 + j];
      dsum += SCF[1] * fcap + PP[j];
      DV[j] = dsum;
    }
    __syncthreads();
    if (tid < 64) {   // LN(dec)
      float a = DV[lane], c = DV[lane + 64];
      float ssum = a + c;
      #pragma unroll
      for (int o = 32; o; o >>= 1) ssum += __shfl_xor(ssum, o, 64);
      const float mu = ssum * (1.f / 128.f);
      const float da = a - mu, dc = c - mu;
      float vv = da * da + dc * dc;
      #pragma unroll
      for (int o = 32; o; o >>= 1) vv += __shfl_xor(vv, o, 64);
      const float inv = 1.0f / sqrtf(vv * (1.f / 128.f) + EPS_);
      DV[lane]      = da * inv * lng[lane] + lnb[lane];
      DV[lane + 64] = dc * inv * lng[lane + 64] + lnb[lane + 64];
    }
    __syncthreads();

    // Phase C: q = d @ wq
    {
      float part = 0.f;
      #pragma unroll
      for (int r = 0; r < 32; ++r) part = fmaf(wq_r[r], DV[s * 32 + r], part);
      RED[s * H_ + j] = part;
    }
    __syncthreads();
    if (tid < 128) QV[j] = RED[j] + RED[128 + j] + RED[256 + j] + RED[384 + j];
    __syncthreads();

    // Phase D: logits (h,n) from LDS K
    for (int t = tid; t < NH_ * N_; t += 512) {
      const int h = t / N_, n = t - h * N_;
      const float* kh = KH + n * SK + h * HD_;
      const float* qh = QV + h * HD_;
      float a0 = 0.f;
      #pragma unroll
      for (int d0 = 0; d0 < HD_; ++d0) a0 = fmaf(qh[d0], kh[d0], a0);
      BUF[h * N_ + n] = (MB[n] > 0.f) ? NEG_INF : a0 * inv_sqrt_hd;
    }
    __syncthreads();

    // Phase E: per-head softmax (one wave per head), in place
    {
      const int h = tid >> 6;
      float* lg = BUF + h * N_;
      float v1 = lg[lane];
      float v2 = (lane + 64 < N_) ? lg[lane + 64] : NEG_INF;
      float mx = fmaxf(v1, v2);
      #pragma unroll
      for (int o = 32; o; o >>= 1) mx = fmaxf(mx, __shfl_xor(mx, o, 64));
      float e1 = expf(v1 - mx);
      float e2 = (lane + 64 < N_) ? expf(v2 - mx) : 0.f;
      float ssum = e1 + e2;
      #pragma unroll
      for (int o = 32; o; o >>= 1) ssum += __shfl_xor(ssum, o, 64);
      lg[lane] = e1 / ssum;
      if (lane + 64 < N_) lg[lane + 64] = e2 / ssum;
    }
    __syncthreads();

    // Phase F: x = attn@V (V in registers) ; x@wo ; LN(ptr)
    {
      const int h = j >> 4;
      const float* aw = BUF + h * N_ + r0;
      float part = 0.f;
      #pragma unroll
      for (int t = 0; t < 26; ++t)
        if (t < nr) part = fmaf(aw[t], vh_r[t], part);
      RED[s * H_ + j] = part;
    }
    __syncthreads();
    if (tid < 128) XV[j] = RED[j] + RED[128 + j] + RED[256 + j] + RED[384 + j];
    __syncthreads();
    {
      float part = 0.f;
      #pragma unroll
      for (int r = 0; r < 32; ++r) part = fmaf(wo_r[r], XV[s * 32 + r], part);
      RED[s * H_ + j] = part;
    }
    __syncthreads();
    if (tid < 128) DV[j] = RED[j] + RED[128 + j] + RED[256 + j] + RED[384 + j];
    __syncthreads();
    if (tid < 64) {   // LN(ptr)
      float a = DV[lane], c = DV[lane + 64];
      float ssum = a + c;
      #pragma unroll
      for (int o = 32; o; o >>= 1) ssum += __shfl_xor(ssum, o, 64);
      const float mu = ssum * (1.f / 128.f);
      const float da = a - mu, dc = c - mu;
      float vv = da * da + dc * dc;
      #pragma unroll
      for (int o = 32; o; o >>= 1) vv += __shfl_xor(vv, o, 64);
      const float inv = 1.0f / sqrtf(vv * (1.f / 128.f) + EPS_);
      DV[lane]      = da * inv * plg[lane] + plb[lane];
      DV[lane + 64] = dc * inv * plg[lane + 64] + plb[lane + 64];
    }
    __syncthreads();

    // Phase G: comp[n] = xn . Kp[n]  via register Kp + wave butterfly reduce
    {
      const float dvj = DV[j];
      #pragma unroll
      for (int t = 0; t < 26; ++t) {
        if (t < nr) {
          float v = dvj * kp_r[t];
          #pragma unroll
          for (int o = 32; o; o >>= 1) v += __shfl_xor(v, o, 64);
          if (lane == 0) RED[w1 * 256 + r0 + t] = v;
        }
      }
    }
    __syncthreads();
    if (tid < N_) {
      const float acc = RED[tid] + RED[256 + tid];
      BUF[tid] = (MB[tid] > 0.f) ? NEG_INF : acc * inv_sqrt_h;
    }
    __syncthreads();

    // pointer softmax, argmax, state update (wave 0)
    if (tid < 64) {
      const bool m1v = (MB[lane] > 0.f);
      const bool m2v = (lane + 64 >= N_) || (MB[lane + 64] > 0.f);
      const bool allmb = __all(m1v && m2v);
      float c1 = BUF[lane] / Tf;
      float c2 = (lane + 64 < N_) ? BUF[lane + 64] / Tf : NEG_INF;
      if (allmb) { c1 = 0.f; c2 = (lane + 64 < N_) ? 0.f : NEG_INF; }
      float mx = fmaxf(c1, c2);
      #pragma unroll
      for (int o = 32; o; o >>= 1) mx = fmaxf(mx, __shfl_xor(mx, o, 64));
      float e1 = expf(c1 - mx);
      float e2 = (lane + 64 < N_) ? expf(c2 - mx) : 0.f;
      float ssum = e1 + e2;
      #pragma unroll
      for (int o = 32; o; o >>= 1) ssum += __shfl_xor(ssum, o, 64);
      float p1 = e1 / ssum + 1e-10f;
      float p2 = (lane + 64 < N_) ? (e2 / ssum + 1e-10f) : 0.f;
      float psum = p1 + p2;
      #pragma unroll
      for (int o = 32; o; o >>= 1) psum += __shfl_xor(psum, o, 64);
      // argmax (first-index tie break)
      float bv = p1; int bi = lane;
      if (p2 > bv) { bv = p2; bi = lane + 64; }
      #pragma unroll
      for (int o = 32; o; o >>= 1) {
        float ov = __shfl_xor(bv, o, 64);
        int   oi = __shfl_xor(bi, o, 64);
        if (ov > bv || (ov == bv && oi < bi)) { bv = ov; bi = oi; }
      }
      float lp = logf(bv / psum);
      if (SCI[3] >= N_ - 1) lp = 0.f;   // done
      if (lane == 0) {
        SCF[2] += lp;
        const float sel = dem[(size_t)b * N_ + bi];
        SCF[1] = (bi == 0) ? capac[b] : (SCF[1] - sel);
        SCI[0] = bi;
        out[(size_t)b * (ns + 2) + 1 + i] = (float)bi;
      }
    }
    __syncthreads();
  }

  if (tid == 0) {
    const int last = SCI[0];
    out[(size_t)b * (ns + 2)] = 0.f;
    out[(size_t)b * (ns + 2) + ns + 1] = (last == 0) ? -1.f : 0.f;
    out[(size_t)Bv * (ns + 2) + b] = SCF[2];   // log_p
  }
}

extern "C" void kernel_launch(void* const* d_in, const int* in_sizes, int n_in,
                              void* d_out, int out_size, void* d_ws, size_t ws_size,
                              hipStream_t stream) {
  const int Bv = in_sizes[0] / (N_ * H_);   // 1024
  const int ns = out_size / Bv - 3;         // B*(ns+2) actions + B log_p  => 120
  gat_decoder<<<dim3(Bv), dim3(512), 0, stream>>>(
      (const float*)d_in[0],  (const float*)d_in[1],  (const float*)d_in[2],
      (const float*)d_in[3],  (const float*)d_in[4],  (const float*)d_in[5],
      (const float*)d_in[6],  (const float*)d_in[7],  (const float*)d_in[8],
      (const float*)d_in[9],  (const float*)d_in[10], (const float*)d_in[11],
      (const float*)d_in[12], (const float*)d_in[13], (const float*)d_in[14],
      (const int*)d_in[16],
      (float*)d_out, Bv, ns);
}